// Round 1
// baseline (96.631 us; speedup 1.0000x reference)
//
#include <hip/hip_runtime.h>

// out[n, 0, h*32 + i, w*32 + j] = x[n, j*32 + i, h, w]
// N=256, C=1024 (B=32), H=W=16.  Pure permutation, HBM-bound.
//
// One block per (n, i): stages the 32x256-float slab x[n, j*32+i, :, :]
// (j = 0..31) through LDS so both global read and global write are
// fully-coalesced float4.

#define NTHREADS 256
#define LDS_PITCH 260   // 32 rows (j) x 260 floats; 1040 B/row keeps b128 writes 16B-aligned

__global__ __launch_bounds__(NTHREADS)
void transposed_pixel_shuffle(const float* __restrict__ x,
                              float* __restrict__ out) {
    __shared__ float lds[32 * LDS_PITCH];   // 33,280 B

    const int t = threadIdx.x;
    const int b = blockIdx.x;
    const int n = b >> 5;    // b / 32
    const int i = b & 31;    // b % 32

    // ---- Phase 1: global -> LDS, coalesced float4 reads ----
    // slab element (j, hw) = x[n, j*32 + i, hw/16, hw%16]
    // global addr = n*262144 + (j*32 + i)*256 + hw
    const float* __restrict__ src_base =
        x + (size_t)n * 262144 + (size_t)i * 256;
    #pragma unroll
    for (int k = 0; k < 8; ++k) {
        const int f  = k * NTHREADS + t;   // float4 index within slab, 0..2047
        const int j  = f >> 6;             // 0..31
        const int hw = (f & 63) << 2;      // 0..252, step 4
        const float4 v = *reinterpret_cast<const float4*>(
            src_base + (size_t)j * 8192 + hw);
        *reinterpret_cast<float4*>(&lds[j * LDS_PITCH + hw]) = v;  // b128, conflict-free
    }
    __syncthreads();

    // ---- Phase 2: LDS -> global, coalesced float4 writes ----
    // out flat (fixed n,i): h*16384 + i*512 + (w*32 + j), 16 runs of 512 floats
    float* __restrict__ dst_base =
        out + (size_t)n * 262144 + (size_t)i * 512;
    #pragma unroll
    for (int k = 0; k < 8; ++k) {
        const int f  = k * NTHREADS + t;
        const int p  = f << 2;         // flat float offset in (h, w*32+j) space, 0..8188
        const int h  = p >> 9;         // 0..15
        const int q  = p & 511;        // w*32 + j0
        const int w  = q >> 5;         // 0..15
        const int j0 = q & 31;         // multiple of 4
        const int hw = h * 16 + w;
        float4 v;
        v.x = lds[(j0 + 0) * LDS_PITCH + hw];
        v.y = lds[(j0 + 1) * LDS_PITCH + hw];
        v.z = lds[(j0 + 2) * LDS_PITCH + hw];
        v.w = lds[(j0 + 3) * LDS_PITCH + hw];
        *reinterpret_cast<float4*>(dst_base + (size_t)h * 16384 + q) = v;
    }
}

extern "C" void kernel_launch(void* const* d_in, const int* in_sizes, int n_in,
                              void* d_out, int out_size, void* d_ws, size_t ws_size,
                              hipStream_t stream) {
    const float* x = (const float*)d_in[0];
    float* out = (float*)d_out;
    const int N = in_sizes[0] / (1024 * 256);   // 256
    const int grid = N * 32;                    // one block per (n, i)
    transposed_pixel_shuffle<<<grid, NTHREADS, 0, stream>>>(x, out);
}

// Round 3
// 87.523 us; speedup vs baseline: 1.1041x; 1.1041x over previous
//
#include <hip/hip_runtime.h>

// out[n, 0, h*32 + i, w*32 + j] = x[n, j*32 + i, h, w]
// N=256, C=1024 (B=32), H=W=16.  Pure permutation, HBM-bound.
//
// One block per (n, i, h-half): stages a 32(j) x 128(hw) float slab through
// LDS so both global read and write are fully-coalesced float4.
// LDS = 16,896 B -> 8 blocks/CU = 32 waves/CU (full occupancy).
// Nontemporal hints on both streams (touch-once data, 512 MB > L3).

#define NTHREADS 256
#define LDS_PITCH 132   // 128 floats/row + 4 pad; row stride 528 B (16B-aligned)

typedef float f4 __attribute__((ext_vector_type(4)));  // native vector: OK for nontemporal builtins

__global__ __launch_bounds__(NTHREADS)
void transposed_pixel_shuffle(const float* __restrict__ x,
                              float* __restrict__ out) {
    __shared__ float lds[32 * LDS_PITCH];   // 16,896 B

    const int t   = threadIdx.x;
    const int b   = blockIdx.x;
    const int n   = b >> 6;          // b / 64
    const int rem = b & 63;
    const int i   = rem >> 1;        // 0..31
    const int h0  = rem & 1;         // h-half: h in [h0*8, h0*8+8)

    // ---- Phase 1: global -> LDS, coalesced float4 reads ----
    // slab element (j, hwl) = x[n, j*32 + i, h0*8 + hwl/16, hwl%16]
    const float* __restrict__ src_base =
        x + (size_t)n * 262144 + (size_t)i * 256 + (size_t)h0 * 128;
    #pragma unroll
    for (int k = 0; k < 4; ++k) {
        const int f   = k * NTHREADS + t;   // float4 index, 0..1023
        const int j   = f >> 5;             // 0..31
        const int hwl = (f & 31) << 2;      // 0..124, step 4
        const f4 v = __builtin_nontemporal_load(
            reinterpret_cast<const f4*>(src_base + (size_t)j * 8192 + hwl));
        *reinterpret_cast<f4*>(&lds[j * LDS_PITCH + hwl]) = v;
    }
    __syncthreads();

    // ---- Phase 2: LDS -> global, coalesced float4 writes ----
    // out flat (fixed n,i,h0): hl*16384 + i*512 + (w*32 + j), 8 runs of 512 floats
    float* __restrict__ dst_base =
        out + (size_t)n * 262144 + (size_t)h0 * 131072 + (size_t)i * 512;
    #pragma unroll
    for (int k = 0; k < 4; ++k) {
        const int f  = k * NTHREADS + t;
        const int p  = f << 2;         // flat offset in (hl, w*32+j) space, 0..4092
        const int hl = p >> 9;         // 0..7
        const int q  = p & 511;        // w*32 + j0
        const int w  = q >> 5;         // 0..15
        const int j0 = q & 31;         // multiple of 4
        const int hw = hl * 16 + w;
        f4 v;
        v.x = lds[(j0 + 0) * LDS_PITCH + hw];
        v.y = lds[(j0 + 1) * LDS_PITCH + hw];
        v.z = lds[(j0 + 2) * LDS_PITCH + hw];
        v.w = lds[(j0 + 3) * LDS_PITCH + hw];
        __builtin_nontemporal_store(v,
            reinterpret_cast<f4*>(dst_base + (size_t)hl * 16384 + q));
    }
}

extern "C" void kernel_launch(void* const* d_in, const int* in_sizes, int n_in,
                              void* d_out, int out_size, void* d_ws, size_t ws_size,
                              hipStream_t stream) {
    const float* x = (const float*)d_in[0];
    float* out = (float*)d_out;
    const int N = in_sizes[0] / (1024 * 256);   // 256
    const int grid = N * 64;                    // one block per (n, i, h-half)
    transposed_pixel_shuffle<<<grid, NTHREADS, 0, stream>>>(x, out);
}